// Round 3
// baseline (13.531 us; speedup 1.0000x reference)
//
#include <hip/hip_runtime.h>
#include <math.h>

#define NN 4096
#define BATCH 64

__device__ __forceinline__ void cmul(float& ar, float& ai, float br, float bi) {
    float nr = ar * br - ai * bi;
    float ni = ar * bi + ai * br;
    ar = nr; ai = ni;
}

// One butterfly stage across lanes (bit `mask` of the 64-lane index):
// new = mine + i * partner   (1/sqrt2 deferred into phase tables)
__device__ __forceinline__ void stage(float& re, float& im, int mask) {
    float pr = __shfl_xor(re, mask);
    float pi = __shfl_xor(im, mask);
    re = re - pi;
    im = im + pr;
}

// Full 6-qubit chain after the input phase: B6, *e^{i a_th}/8, B6, *e^{i a_ph}/8
__device__ __forceinline__ void chain6(float& re, float& im, float a_th, float a_ph) {
    #pragma unroll
    for (int m = 0; m < 6; ++m) stage(re, im, 1 << m);
    float s, c;
    __sincosf(a_th, &s, &c);
    cmul(re, im, c * 0.125f, s * 0.125f);
    #pragma unroll
    for (int m = 0; m < 6; ++m) stage(re, im, 1 << m);
    __sincosf(a_ph, &s, &c);
    cmul(re, im, c * 0.125f, s * 0.125f);
}

// Kernel A: lo-axis (qubits 6..11). One wave per (b,h) row; writes Z[b][l][h].
__global__ __launch_bounds__(512) void kA(
    const float* __restrict__ x,
    const float* __restrict__ al, const float* __restrict__ be,
    const float* __restrict__ th, const float* __restrict__ ph,
    float2* __restrict__ Z)
{
    __shared__ float tre[8][68], tim[8][68];   // 68: 4*dh+l2 covers all 32 banks
    const int t = threadIdx.x;
    const int w = t >> 6;
    const int l = t & 63;
    const int b  = blockIdx.x >> 3;
    const int h0 = (blockIdx.x & 7) * 8;
    const int h  = h0 + w;

    float re = x[(size_t)b * 2 * NN + h * 64 + l];
    float im = x[(size_t)b * 2 * NN + NN + h * 64 + l];

    float a_in = 0.f, a_th = 0.f, a_ph = 0.f;
    #pragma unroll
    for (int m = 0; m < 6; ++m) {           // qubit q = 6+m  <->  bit (5-m) of l
        int bit = (l >> (5 - m)) & 1;
        int q = 6 + m;
        a_in += bit ? be[q] : al[q];
        if (!bit) { a_th += th[q]; a_ph += ph[q]; }
    }
    float s, c;
    __sincosf(a_in, &s, &c);
    cmul(re, im, c, s);
    chain6(re, im, a_th, a_ph);

    // transpose 8x64 tile -> Z[b][l][h] so kernel B reads coalesced rows
    tre[w][l] = re; tim[w][l] = im;
    __syncthreads();
    const int l2 = t >> 3, dh = t & 7;
    float2 v = make_float2(tre[dh][l2], tim[dh][l2]);
    Z[(size_t)b * NN + l2 * 64 + h0 + dh] = v;
}

// Kernel B: hi-axis (qubits 0..5). One wave per (b,l') row of Z; writes out.
__global__ __launch_bounds__(512) void kB(
    const float2* __restrict__ Z,
    const float* __restrict__ al, const float* __restrict__ be,
    const float* __restrict__ th, const float* __restrict__ ph,
    float* __restrict__ out)
{
    __shared__ float tre[64][9], tim[64][9];
    const int t = threadIdx.x;
    const int w = t >> 6;
    const int lane = t & 63;                 // = h during the chain
    const int b  = blockIdx.x >> 3;
    const int l0 = (blockIdx.x & 7) * 8;

    float2 v = Z[(size_t)b * NN + (l0 + w) * 64 + lane];
    float re = v.x, im = v.y;

    float a_in = 0.f, a_th = 0.f, a_ph = 0.f;
    #pragma unroll
    for (int q = 0; q < 6; ++q) {            // qubit q <-> bit (5-q) of h
        int bit = (lane >> (5 - q)) & 1;
        a_in += bit ? be[q] : al[q];
        if (!bit) { a_th += th[q]; a_ph += ph[q]; }
    }
    float s, c;
    __sincosf(a_in, &s, &c);
    cmul(re, im, c, s);
    chain6(re, im, a_th, a_ph);

    // lane h holds out[b][h][l0+w]; transpose for coalesced-ish plane writes
    tre[lane][w] = re; tim[lane][w] = im;
    __syncthreads();
    const int h = t >> 3, dl = t & 7;
    out[(size_t)b * 2 * NN + h * 64 + l0 + dl]      = tre[h][dl];
    out[(size_t)b * 2 * NN + NN + h * 64 + l0 + dl] = tim[h][dl];
}

// ---------------- fallback (round-2 kernel) if ws too small ----------------
#define BLK 512
#define EPT 8
#define EXSZ (NN + (NN >> 5))

__device__ __forceinline__ void bfly_pair(float* vr, float* vi, int a, int b) {
    float ur = vr[a], ui = vi[a], wr = vr[b], wi = vi[b];
    vr[a] = ur - wi; vi[a] = ui + wr;
    vr[b] = wr - ui; vi[b] = wi + ur;
}
__device__ __forceinline__ void bfly3(float* vr, float* vi) {
    bfly_pair(vr, vi, 0, 1); bfly_pair(vr, vi, 2, 3); bfly_pair(vr, vi, 4, 5); bfly_pair(vr, vi, 6, 7);
    bfly_pair(vr, vi, 0, 2); bfly_pair(vr, vi, 1, 3); bfly_pair(vr, vi, 4, 6); bfly_pair(vr, vi, 5, 7);
    bfly_pair(vr, vi, 0, 4); bfly_pair(vr, vi, 1, 5); bfly_pair(vr, vi, 2, 6); bfly_pair(vr, vi, 3, 7);
}
template<int PC, int PN>
__device__ __forceinline__ void exchange(float2* ex, float* vr, float* vi, int t) {
    const int basec = ((t >> PC) << (PC + 3)) | (t & ((1 << PC) - 1));
    #pragma unroll
    for (int r = 0; r < EPT; ++r) { int j = basec + (r << PC); ex[j + (j >> 5)] = make_float2(vr[r], vi[r]); }
    __syncthreads();
    const int basen = ((t >> PN) << (PN + 3)) | (t & ((1 << PN) - 1));
    #pragma unroll
    for (int r = 0; r < EPT; ++r) { int j = basen + (r << PN); float2 v = ex[j + (j >> 5)]; vr[r] = v.x; vi[r] = v.y; }
}
__global__ __launch_bounds__(BLK) void qubit_layer_fb(
    const float* __restrict__ x, const float* __restrict__ alphas, const float* __restrict__ betas,
    const float* __restrict__ thetas, const float* __restrict__ phis, float* __restrict__ out)
{
    __shared__ float2 ex0[EXSZ];
    __shared__ float2 ex1[EXSZ];
    __shared__ float2 tbl[6][64];
    const int b = blockIdx.x;
    const int t = threadIdx.x;
    if (t < 384) {
        int part = t >> 6, idx = t & 63, set = part >> 1, half = part & 1;
        float a = 0.f;
        #pragma unroll
        for (int m = 0; m < 6; ++m) {
            int q = half ? m : (6 + m);
            int bit = (idx >> (5 - m)) & 1;
            float av, bv;
            if (set == 0)      { av = alphas[q]; bv = betas[q]; }
            else if (set == 1) { av = thetas[q]; bv = 0.f; }
            else               { av = phis[q];   bv = 0.f; }
            a += bit ? bv : av;
        }
        float s, c; __sincosf(a, &s, &c);
        float sc = (set >= 1 && half == 0) ? (1.0f / 64.0f) : 1.0f;
        tbl[part][idx] = make_float2(c * sc, s * sc);
    }
    float vr[EPT], vi[EPT];
    const float* xr = x + (size_t)b * 2 * NN;
    const float* xi = xr + NN;
    {
        float4 a0 = ((const float4*)(xr + t * EPT))[0];
        float4 a1 = ((const float4*)(xr + t * EPT))[1];
        float4 c0 = ((const float4*)(xi + t * EPT))[0];
        float4 c1 = ((const float4*)(xi + t * EPT))[1];
        vr[0]=a0.x; vr[1]=a0.y; vr[2]=a0.z; vr[3]=a0.w; vr[4]=a1.x; vr[5]=a1.y; vr[6]=a1.z; vr[7]=a1.w;
        vi[0]=c0.x; vi[1]=c0.y; vi[2]=c0.z; vi[3]=c0.w; vi[4]=c1.x; vi[5]=c1.y; vi[6]=c1.z; vi[7]=c1.w;
    }
    __syncthreads();
    {
        float2 eh = tbl[1][t >> 3];
        #pragma unroll
        for (int r = 0; r < EPT; ++r) {
            float2 el = tbl[0][((t & 7) << 3) + r];
            float er = el.x, ei = el.y;
            cmul(er, ei, eh.x, eh.y);
            cmul(vr[r], vi[r], er, ei);
        }
    }
    bfly3(vr, vi);
    exchange<0, 3>(ex0, vr, vi, t); bfly3(vr, vi);
    exchange<3, 6>(ex1, vr, vi, t); bfly3(vr, vi);
    exchange<6, 9>(ex0, vr, vi, t); bfly3(vr, vi);
    {
        float2 el = tbl[2][t & 63];
        #pragma unroll
        for (int r = 0; r < EPT; ++r) {
            float2 eh = tbl[3][(t >> 6) + (r << 3)];
            float er = el.x, ei = el.y;
            cmul(er, ei, eh.x, eh.y);
            cmul(vr[r], vi[r], er, ei);
        }
    }
    exchange<9, 0>(ex1, vr, vi, t); bfly3(vr, vi);
    exchange<0, 3>(ex0, vr, vi, t); bfly3(vr, vi);
    exchange<3, 6>(ex1, vr, vi, t); bfly3(vr, vi);
    exchange<6, 9>(ex0, vr, vi, t); bfly3(vr, vi);
    float* outr = out + (size_t)b * 2 * NN;
    float* outi = outr + NN;
    {
        float2 el = tbl[4][t & 63];
        #pragma unroll
        for (int r = 0; r < EPT; ++r) {
            float2 eh = tbl[5][(t >> 6) + (r << 3)];
            float er = el.x, ei = el.y;
            cmul(er, ei, eh.x, eh.y);
            cmul(vr[r], vi[r], er, ei);
            outr[t + (r << 9)] = vr[r];
            outi[t + (r << 9)] = vi[r];
        }
    }
}

extern "C" void kernel_launch(void* const* d_in, const int* in_sizes, int n_in,
                              void* d_out, int out_size, void* d_ws, size_t ws_size,
                              hipStream_t stream) {
    const float* x      = (const float*)d_in[0];
    const float* alphas = (const float*)d_in[1];
    const float* betas  = (const float*)d_in[2];
    const float* thetas = (const float*)d_in[3];
    const float* phis   = (const float*)d_in[4];
    float* out = (float*)d_out;
    const int batch = in_sizes[0] / (2 * NN);          // 64

    const size_t zbytes = (size_t)batch * NN * sizeof(float2);
    if (ws_size >= zbytes) {
        float2* Z = (float2*)d_ws;
        kA<<<batch * 8, 512, 0, stream>>>(x, alphas, betas, thetas, phis, Z);
        kB<<<batch * 8, 512, 0, stream>>>(Z, alphas, betas, thetas, phis, out);
    } else {
        qubit_layer_fb<<<batch, BLK, 0, stream>>>(x, alphas, betas, thetas, phis, out);
    }
}